// Round 4
// baseline (667.774 us; speedup 1.0000x reference)
//
#include <hip/hip_runtime.h>
#include <math.h>

#define S_LEN 2048
#define DMODEL 512
#define NHEAD 8
#define BATCH 4
#define M_ROWS (BATCH * S_LEN)   // 8192
#define UAC 4194304              // M_ROWS * DMODEL (elements per activation unit)

typedef __attribute__((ext_vector_type(8))) short frag8;   // 8 bf16 (4 VGPRs)
typedef __attribute__((ext_vector_type(4))) float f32x4;   // MFMA accumulator

__device__ inline unsigned short f2bf(float f) {
    unsigned int u = __float_as_uint(f);
    return (unsigned short)((u + 0x7FFFu + ((u >> 16) & 1u)) >> 16);  // RNE
}
__device__ inline float bf2f(unsigned short h) {
    return __uint_as_float(((unsigned int)h) << 16);
}

// ---------------------------------------------------------------------------
// Fused weight transpose+cast: 12 segments, one launch. W(K,N) f32 -> Wt(N,K) bf16.
// ---------------------------------------------------------------------------
struct WSeg { const float* src; unsigned short* dst; int K; int N; int start; };
struct WTab { WSeg s[12]; };

__global__ __launch_bounds__(256) void wcast_all(WTab tab)
{
    __shared__ float t[32][33];
    const int bid = blockIdx.x;
    int si = 0;
#pragma unroll
    for (int i = 1; i < 12; ++i) if (bid >= tab.s[i].start) si = i;
    const WSeg sg = tab.s[si];
    const int tile = bid - sg.start;
    const int nk = sg.K >> 5;
    const int k0 = (tile % nk) * 32, n0 = (tile / nk) * 32;
    {
        int kk = threadIdx.x >> 3, nq = (threadIdx.x & 7) * 4;
        float4 v = *(const float4*)&sg.src[(size_t)(k0 + kk) * sg.N + n0 + nq];
        t[kk][nq + 0] = v.x; t[kk][nq + 1] = v.y; t[kk][nq + 2] = v.z; t[kk][nq + 3] = v.w;
    }
    __syncthreads();
    {
        int n = threadIdx.x >> 3, kq = (threadIdx.x & 7) * 4;
        ushort4 o;
        o.x = f2bf(t[kq + 0][n]); o.y = f2bf(t[kq + 1][n]);
        o.z = f2bf(t[kq + 2][n]); o.w = f2bf(t[kq + 3][n]);
        *(ushort4*)&sg.dst[(size_t)(n0 + n) * sg.K + k0 + kq] = o;
    }
}

// ---------------------------------------------------------------------------
// V transpose: V(B,S,512) bf16 -> Vt(B*H, 64, S) bf16. grid (S/64, B*H).
// ---------------------------------------------------------------------------
__global__ __launch_bounds__(256) void vtrans_kernel(
    const unsigned short* __restrict__ V, unsigned short* __restrict__ Vt)
{
    __shared__ unsigned short T[64][72];
    const int st = blockIdx.x, bh = blockIdx.y;
    const int b = bh >> 3, h = bh & 7;
    const int tid = threadIdx.x;
    {
        const int s = tid >> 2, d0 = (tid & 3) * 16;
        const unsigned short* src = V + ((size_t)(b * S_LEN + st * 64 + s) * DMODEL + h * 64 + d0);
        *(uint4*)&T[s][d0] = *(const uint4*)src;
        *(uint4*)&T[s][d0 + 8] = *(const uint4*)(src + 8);
    }
    __syncthreads();
    {
        const int d = tid >> 2, s0 = (tid & 3) * 16;
        unsigned short buf[16];
#pragma unroll
        for (int j = 0; j < 16; ++j) buf[j] = T[s0 + j][d];
        unsigned short* dst = Vt + ((size_t)(bh * 64 + d) * S_LEN + st * 64 + s0);
        *(uint4*)&dst[0] = *(const uint4*)&buf[0];
        *(uint4*)&dst[8] = *(const uint4*)&buf[8];
    }
}

// ---------------------------------------------------------------------------
// MFMA GEMM with register-prefetch pipelining.
// C = A(M,K) @ Wt(N,K)^T + bias.  Modes:
//   0: bias   1: bias+pos (A f32)   2: relu   3: gate blend (K=1024)
//   5: fused QKV (N=1536): out[mat*UAC + m*512 + (n&511)], mat0 (Q) scaled 1/8
// BM=128 BN=64 BK=64, 256 thr = 4 waves, wave tile 64x32.
// ---------------------------------------------------------------------------
template <int MODE>
__global__ __launch_bounds__(256) void gemm_mfma(
    const void* __restrict__ Av, const unsigned short* __restrict__ A2,
    const unsigned short* __restrict__ Wt, const float* __restrict__ bias,
    const float* __restrict__ pos, unsigned short* __restrict__ C,
    int M, int N, int K)
{
    __shared__ unsigned short As[128][72];
    __shared__ unsigned short Bs[64][72];
    const int tid = threadIdx.x;
    const int wave = tid >> 6, lane = tid & 63;
    const int lr = lane & 15, quad = lane >> 4, q8 = quad * 8;
    const int bm = blockIdx.x * 128, bn = blockIdx.y * 64;
    const int rm = (wave >> 1) * 64, rn = (wave & 1) * 32;
    const int Khalf = K >> 1;

    const int am = tid >> 1, akh = (tid & 1) * 32;     // A staging: row, k-offset (32 shorts)
    const int bnr = tid >> 2, bkq = (tid & 3) * 16;    // B staging: row, k-offset (16 shorts)

    uint4 ra[4], rb[2];
    float4 fa[8];

    auto loadA = [&](int k0) {
        if constexpr (MODE == 1) {
            const float* src = (const float*)Av + (size_t)(bm + am) * K + k0 + akh;
#pragma unroll
            for (int i = 0; i < 8; ++i) fa[i] = *(const float4*)(src + i * 4);
        } else if constexpr (MODE == 3) {
            const int kk = k0 + akh;
            const unsigned short* src = (kk < Khalf)
                ? (const unsigned short*)Av + (size_t)(bm + am) * Khalf + kk
                : A2 + (size_t)(bm + am) * Khalf + (kk - Khalf);
#pragma unroll
            for (int i = 0; i < 4; ++i) ra[i] = *(const uint4*)(src + i * 8);
        } else {
            const unsigned short* src = (const unsigned short*)Av + (size_t)(bm + am) * K + k0 + akh;
#pragma unroll
            for (int i = 0; i < 4; ++i) ra[i] = *(const uint4*)(src + i * 8);
        }
    };
    auto loadB = [&](int k0) {
        const unsigned short* src = Wt + (size_t)(bn + bnr) * K + k0 + bkq;
        rb[0] = *(const uint4*)src;
        rb[1] = *(const uint4*)(src + 8);
    };

    f32x4 acc[4][2];
#pragma unroll
    for (int t = 0; t < 4; ++t)
#pragma unroll
        for (int u = 0; u < 2; ++u) acc[t][u] = (f32x4){0.f, 0.f, 0.f, 0.f};

    loadA(0); loadB(0);
    for (int k0 = 0; k0 < K; k0 += 64) {
        if (k0) __syncthreads();       // previous iteration's frag reads complete
        if constexpr (MODE == 1) {
#pragma unroll
            for (int i = 0; i < 4; ++i) {
                float4 v0 = fa[i * 2], v1 = fa[i * 2 + 1];
                unsigned short us[8];
                us[0] = f2bf(v0.x); us[1] = f2bf(v0.y); us[2] = f2bf(v0.z); us[3] = f2bf(v0.w);
                us[4] = f2bf(v1.x); us[5] = f2bf(v1.y); us[6] = f2bf(v1.z); us[7] = f2bf(v1.w);
                *(uint4*)&As[am][akh + i * 8] = *(uint4*)us;
            }
        } else {
#pragma unroll
            for (int i = 0; i < 4; ++i) *(uint4*)&As[am][akh + i * 8] = ra[i];
        }
        *(uint4*)&Bs[bnr][bkq] = rb[0];
        *(uint4*)&Bs[bnr][bkq + 8] = rb[1];
        if (k0 + 64 < K) { loadA(k0 + 64); loadB(k0 + 64); }   // prefetch next tile
        __syncthreads();
#pragma unroll
        for (int kc = 0; kc < 2; ++kc) {
            frag8 af[4], bfr[2];
#pragma unroll
            for (int t = 0; t < 4; ++t)
                af[t] = *(const frag8*)&As[rm + t * 16 + lr][kc * 32 + q8];
#pragma unroll
            for (int u = 0; u < 2; ++u)
                bfr[u] = *(const frag8*)&Bs[rn + u * 16 + lr][kc * 32 + q8];
#pragma unroll
            for (int t = 0; t < 4; ++t)
#pragma unroll
                for (int u = 0; u < 2; ++u)
                    acc[t][u] = __builtin_amdgcn_mfma_f32_16x16x32_bf16(
                        af[t], bfr[u], acc[t][u], 0, 0, 0);
        }
    }

    // ---- epilogue ----
#pragma unroll
    for (int t = 0; t < 4; ++t) {
#pragma unroll
        for (int i = 0; i < 4; ++i) {
            const int m = bm + rm + t * 16 + quad * 4 + i;
#pragma unroll
            for (int u = 0; u < 2; ++u) {
                const int n = bn + rn + u * 16 + lr;
                float v = acc[t][u][i] + bias[n];
                if constexpr (MODE == 1) v += pos[(size_t)(m & (S_LEN - 1)) * N + n];
                if constexpr (MODE == 2) v = fmaxf(v, 0.0f);
                if constexpr (MODE == 3) {
                    float g = tanhf(fmaxf(v, 0.0f));
                    float lo = bf2f(((const unsigned short*)Av)[(size_t)m * Khalf + n]);
                    float go = bf2f(A2[(size_t)m * Khalf + n]);
                    v = g * lo + (1.0f - g) * go;
                }
                if constexpr (MODE == 5) {
                    const int mat = n >> 9;
                    if (mat == 0) v *= 0.125f;          // fold attn scale into Q
                    C[(size_t)mat * UAC + (size_t)m * DMODEL + (n & 511)] = f2bf(v);
                } else {
                    C[(size_t)m * N + n] = f2bf(v);
                }
            }
        }
    }
}

// ---------------------------------------------------------------------------
// MFMA flash attention, transposed-S formulation, max-free softmax.
// Q,K: (B,S,512) bf16 (Q pre-scaled by 1/8); Vt: (B*H,64,S) bf16; O: (B,S,512).
// Block = 256 thr = 4 waves; wave handles 16 q-rows; 64x64 tiles.
// S^T = K·Q^T puts 4 consecutive c per lane -> P written with ds_write_b64.
// Ps is wave-private (doubles as Q staging). K/Vt staged with reg prefetch.
// ---------------------------------------------------------------------------
__global__ __launch_bounds__(256) void attn_mfma(
    const unsigned short* __restrict__ Q, const unsigned short* __restrict__ Kv,
    const unsigned short* __restrict__ Vt, unsigned short* __restrict__ O, int masked)
{
    __shared__ unsigned short Ks[64][72];   // [c][d]
    __shared__ unsigned short Vts[64][72];  // [d][c]
    __shared__ unsigned short Ps[64][72];   // [q][c]; also Q staging [q][d]
    const int qt = blockIdx.x, h = blockIdx.y, b = blockIdx.z;
    const int tid = threadIdx.x;
    const int wave = tid >> 6, lane = tid & 63;
    const int lr = lane & 15, quad = lane >> 4, q8 = quad * 8;

    // stage Q (wave-private rows) and hoist fragments
    {
        const int q = tid >> 2, d0 = (tid & 3) * 16;
        const unsigned short* src = Q + ((size_t)(b * S_LEN + qt * 64 + q) * DMODEL + h * 64 + d0);
        *(uint4*)&Ps[q][d0] = *(const uint4*)src;
        *(uint4*)&Ps[q][d0 + 8] = *(const uint4*)(src + 8);
    }
    frag8 qf[2];
    qf[0] = *(const frag8*)&Ps[wave * 16 + lr][q8];
    qf[1] = *(const frag8*)&Ps[wave * 16 + lr][32 + q8];

    f32x4 oacc[4];
#pragma unroll
    for (int t = 0; t < 4; ++t) oacc[t] = (f32x4){0.f, 0.f, 0.f, 0.f};
    float l_r = 0.f;                       // per-lane partial row sum (row = lr)

    int kt0 = 0, kt1 = S_LEN / 64 - 1;
    if (masked) { kt0 = qt > 0 ? qt - 1 : 0; kt1 = qt < 31 ? qt + 1 : 31; }

    // K/Vt staging coords + prefetch registers
    const int sc = tid >> 2, sd0 = (tid & 3) * 16;   // K: row c, d-offset
    uint4 rk0, rk1, rv0, rv1;
    auto loadKV = [&](int kt) {
        const unsigned short* ksrc = Kv + ((size_t)(b * S_LEN + kt * 64 + sc) * DMODEL + h * 64 + sd0);
        rk0 = *(const uint4*)ksrc; rk1 = *(const uint4*)(ksrc + 8);
        const unsigned short* vsrc = Vt + ((size_t)((b * 8 + h) * 64 + sc) * S_LEN + kt * 64 + sd0);
        rv0 = *(const uint4*)vsrc; rv1 = *(const uint4*)(vsrc + 8);
    };
    loadKV(kt0);

    for (int kt = kt0; kt <= kt1; ++kt) {
        if (kt > kt0) __syncthreads();     // prev iteration's frag reads done
        *(uint4*)&Ks[sc][sd0] = rk0;  *(uint4*)&Ks[sc][sd0 + 8] = rk1;
        *(uint4*)&Vts[sc][sd0] = rv0; *(uint4*)&Vts[sc][sd0 + 8] = rv1;
        if (kt < kt1) loadKV(kt + 1);      // prefetch next K/V tile
        __syncthreads();

        // ---- S^T = K Q^T : lane holds S[q=lr][c = t*16 + quad*4 + i] ----
        f32x4 sacc[4];
#pragma unroll
        for (int t = 0; t < 4; ++t) sacc[t] = (f32x4){0.f, 0.f, 0.f, 0.f};
#pragma unroll
        for (int kc = 0; kc < 2; ++kc) {
#pragma unroll
            for (int t = 0; t < 4; ++t) {
                frag8 kf = *(const frag8*)&Ks[t * 16 + lr][kc * 32 + q8];
                sacc[t] = __builtin_amdgcn_mfma_f32_16x16x32_bf16(kf, qf[kc], sacc[t], 0, 0, 0);
            }
        }

        // ---- max-free softmax; contiguous-c pack -> one b64 write per t ----
#pragma unroll
        for (int t = 0; t < 4; ++t) {
            float p[4];
#pragma unroll
            for (int i = 0; i < 4; ++i) p[i] = __expf(sacc[t][i]);
            if (masked) {
                const int qa = qt * 64 + wave * 16 + lr;
                const int ca = kt * 64 + t * 16 + quad * 4;
#pragma unroll
                for (int i = 0; i < 4; ++i) {
                    const int d = qa - (ca + i);
                    if (d > 32 || d < -32) p[i] = 0.f;
                }
            }
            l_r += (p[0] + p[1]) + (p[2] + p[3]);
            ushort4 pk;
            pk.x = f2bf(p[0]); pk.y = f2bf(p[1]); pk.z = f2bf(p[2]); pk.w = f2bf(p[3]);
            *(ushort4*)&Ps[wave * 16 + lr][t * 16 + quad * 4] = pk;
        }
        // no barrier: Ps rows [16w,16w+16) written and read only by wave w

        // ---- O += P V ----
#pragma unroll
        for (int cc = 0; cc < 2; ++cc) {
            frag8 pa = *(const frag8*)&Ps[wave * 16 + lr][cc * 32 + q8];
#pragma unroll
            for (int t = 0; t < 4; ++t) {
                frag8 vf = *(const frag8*)&Vts[t * 16 + lr][cc * 32 + q8];
                oacc[t] = __builtin_amdgcn_mfma_f32_16x16x32_bf16(pa, vf, oacc[t], 0, 0, 0);
            }
        }
    }

    // ---- one deferred row-sum reduction + epilogue ----
    l_r += __shfl_xor(l_r, 16);
    l_r += __shfl_xor(l_r, 32);            // lanes with same lr now hold row-lr sum
#pragma unroll
    for (int i = 0; i < 4; ++i) {
        const float inv = 1.0f / __shfl(l_r, quad * 4 + i);
        const int q = qt * 64 + wave * 16 + quad * 4 + i;
#pragma unroll
        for (int t = 0; t < 4; ++t)
            O[(size_t)(b * S_LEN + q) * DMODEL + h * 64 + t * 16 + lr] = f2bf(oacc[t][i] * inv);
    }
}

// ---------------------------------------------------------------------------
// LayerNorm (bf16 in/out, fp32 math): 256-thr blocks, one wave per row.
// ---------------------------------------------------------------------------
__device__ inline float wave_sum64(float v) {
#pragma unroll
    for (int off = 1; off < 64; off <<= 1) v += __shfl_xor(v, off);
    return v;
}

__global__ __launch_bounds__(256) void ln_res_kernel(
    const unsigned short* __restrict__ A, const unsigned short* __restrict__ Bb,
    const float* __restrict__ g, const float* __restrict__ be,
    unsigned short* __restrict__ out)
{
    const size_t row = blockIdx.x * 4 + (threadIdx.x >> 6);
    const int lane = threadIdx.x & 63;
    float x[8]; float s = 0.f;
#pragma unroll
    for (int k = 0; k < 8; ++k) {
        size_t idx = row * DMODEL + k * 64 + lane;
        x[k] = bf2f(A[idx]) + bf2f(Bb[idx]);
        s += x[k];
    }
    s = wave_sum64(s);
    float mean = s * (1.0f / DMODEL);
    float v = 0.f;
#pragma unroll
    for (int k = 0; k < 8; ++k) { float d = x[k] - mean; v += d * d; }
    v = wave_sum64(v) * (1.0f / DMODEL);
    float r = rsqrtf(v + 1e-5f);
#pragma unroll
    for (int k = 0; k < 8; ++k)
        out[row * DMODEL + k * 64 + lane] =
            f2bf((x[k] - mean) * r * g[k * 64 + lane] + be[k * 64 + lane]);
}

__global__ __launch_bounds__(256) void ln_double_kernel(
    const unsigned short* __restrict__ A, const unsigned short* __restrict__ Bb,
    const float* __restrict__ g2, const float* __restrict__ b2,
    const float* __restrict__ g3, const float* __restrict__ b3,
    unsigned short* __restrict__ out)
{
    const size_t row = blockIdx.x * 4 + (threadIdx.x >> 6);
    const int lane = threadIdx.x & 63;
    float x[8]; float s = 0.f;
#pragma unroll
    for (int k = 0; k < 8; ++k) {
        size_t idx = row * DMODEL + k * 64 + lane;
        x[k] = bf2f(A[idx]) + bf2f(Bb[idx]);
        s += x[k];
    }
    s = wave_sum64(s);
    float mean = s * (1.0f / DMODEL);
    float v = 0.f;
#pragma unroll
    for (int k = 0; k < 8; ++k) { float d = x[k] - mean; v += d * d; }
    v = wave_sum64(v) * (1.0f / DMODEL);
    float r = rsqrtf(v + 1e-5f);
    float t[8]; float s2 = 0.f;
#pragma unroll
    for (int k = 0; k < 8; ++k) {
        t[k] = (x[k] - mean) * r * g2[k * 64 + lane] + b2[k * 64 + lane];
        s2 += t[k];
    }
    s2 = wave_sum64(s2);
    float mean2 = s2 * (1.0f / DMODEL);
    float v2 = 0.f;
#pragma unroll
    for (int k = 0; k < 8; ++k) { float d = t[k] - mean2; v2 += d * d; }
    v2 = wave_sum64(v2) * (1.0f / DMODEL);
    float r2 = rsqrtf(v2 + 1e-5f);
#pragma unroll
    for (int k = 0; k < 8; ++k)
        out[row * DMODEL + k * 64 + lane] =
            f2bf((t[k] - mean2) * r2 * g3[k * 64 + lane] + b3[k * 64 + lane]);
}

// ---------------------------------------------------------------------------
// Mean-pool over S (bf16 in, fp32 atomics) + tiny final GEMM (fp32).
// ---------------------------------------------------------------------------
__global__ __launch_bounds__(256) void pool_kernel(
    const unsigned short* __restrict__ h2, float* __restrict__ pooled)
{
    const int b = blockIdx.x >> 4;
    const int chunk = blockIdx.x & 15;
    const int tid = threadIdx.x;
    float s0 = 0.f, s1 = 0.f;
    size_t base = (size_t)(b * S_LEN + chunk * 128) * DMODEL;
    for (int r = 0; r < 128; ++r) {
        s0 += bf2f(h2[base + (size_t)r * DMODEL + tid]);
        s1 += bf2f(h2[base + (size_t)r * DMODEL + 256 + tid]);
    }
    atomicAdd(&pooled[b * DMODEL + tid], s0);
    atomicAdd(&pooled[b * DMODEL + 256 + tid], s1);
}

__global__ __launch_bounds__(128) void out_kernel(
    const float* __restrict__ pooled, const float* __restrict__ w,
    const float* __restrict__ bias, float* __restrict__ out)
{
    const int b = blockIdx.x;
    const int o = threadIdx.x;
    float acc = 0.f;
    for (int d = 0; d < DMODEL; ++d)
        acc += pooled[b * DMODEL + d] * w[d * 128 + o];
    out[b * 128 + o] = acc * (1.0f / S_LEN) + bias[o];
}

// ---------------------------------------------------------------------------
extern "C" void kernel_launch(void* const* d_in, const int* in_sizes, int n_in,
                              void* d_out, int out_size, void* d_ws, size_t ws_size,
                              hipStream_t stream)
{
    const float* x      = (const float*)d_in[0];
    const float* pos    = (const float*)d_in[1];
    const float* win_w  = (const float*)d_in[2];
    const float* win_b  = (const float*)d_in[3];
    const float* l_wqkv = (const float*)d_in[4];
    const float* l_bqkv = (const float*)d_in[5];
    const float* l_wo   = (const float*)d_in[6];
    const float* l_bo   = (const float*)d_in[7];
    const float* g_wqkv = (const float*)d_in[8];
    const float* g_bqkv = (const float*)d_in[9];
    const float* g_wo   = (const float*)d_in[10];
    const float* g_bo   = (const float*)d_in[11];
    const float* gate_w = (const float*)d_in[12];
    const float* gate_b = (const float*)d_in[13];
    const float* ffn_w1 = (const float*)d_in[14];
    const float* ffn_b1 = (const float*)d_in[15];
    const float* ffn_w2 = (const float*)d_in[16];
    const float* ffn_b2 = (const float*)d_in[17];
    const float* n1_g   = (const float*)d_in[18];
    const float* n1_b   = (const float*)d_in[19];
    const float* n2_g   = (const float*)d_in[20];
    const float* n2_b   = (const float*)d_in[21];
    const float* n3_g   = (const float*)d_in[22];
    const float* n3_b   = (const float*)d_in[23];
    const float* out_w  = (const float*)d_in[24];
    const float* out_b  = (const float*)d_in[25];
    float* out = (float*)d_out;

    unsigned short* ws16 = (unsigned short*)d_ws;
    const size_t UA = (size_t)UAC;
    unsigned short* H  = ws16 + 0 * UA;
    unsigned short* Qb = ws16 + 1 * UA;
    unsigned short* Kb = ws16 + 2 * UA;
    unsigned short* Vb = ws16 + 3 * UA;
    unsigned short* AO = ws16 + 4 * UA;
    unsigned short* LO = ws16 + 5 * UA;
    unsigned short* VT = ws16 + 6 * UA;     // transposed V (B*H,64,S)
    unsigned short* GO     = Qb;            // Q dead after global attn
    unsigned short* FUSED  = Kb;            // K dead after global attn
    unsigned short* H1     = Vb;            // V dead after global attn
    unsigned short* FFNMID = AO;            // spans units 4..5
    unsigned short* FFNOUT = Qb;            // GO dead after gate
    unsigned short* H2     = Kb;            // FUSED dead after LN1
    float* POOLED = (float*)(void*)H;       // H dead after LN1

    // transposed bf16 weights
    unsigned short* wt = ws16 + 7 * UA;
    unsigned short* win_t  = wt;                      // 512 x 256
    unsigned short* lqkv_t = win_t  + 131072;         // 3 x (512 x 512)
    unsigned short* lwo_t  = lqkv_t + 786432;
    unsigned short* gqkv_t = lwo_t  + 262144;
    unsigned short* gwo_t  = gqkv_t + 786432;
    unsigned short* gate_t = gwo_t  + 262144;         // 512 x 1024
    unsigned short* ffn1_t = gate_t + 524288;         // 1024 x 512
    unsigned short* ffn2_t = ffn1_t + 524288;         // 512 x 1024

    WTab tab;
    tab.s[0]  = {win_w,             win_t,             256,  512,    0};
    tab.s[1]  = {l_wqkv + 0*262144, lqkv_t + 0*262144, 512,  512,  128};
    tab.s[2]  = {l_wqkv + 1*262144, lqkv_t + 1*262144, 512,  512,  384};
    tab.s[3]  = {l_wqkv + 2*262144, lqkv_t + 2*262144, 512,  512,  640};
    tab.s[4]  = {l_wo,              lwo_t,             512,  512,  896};
    tab.s[5]  = {g_wqkv + 0*262144, gqkv_t + 0*262144, 512,  512, 1152};
    tab.s[6]  = {g_wqkv + 1*262144, gqkv_t + 1*262144, 512,  512, 1408};
    tab.s[7]  = {g_wqkv + 2*262144, gqkv_t + 2*262144, 512,  512, 1664};
    tab.s[8]  = {g_wo,              gwo_t,             512,  512, 1920};
    tab.s[9]  = {gate_w,            gate_t,            1024, 512, 2176};
    tab.s[10] = {ffn_w1,            ffn1_t,            512, 1024, 2688};
    tab.s[11] = {ffn_w2,            ffn2_t,            1024, 512, 3200};

    dim3 blk(256);
    wcast_all<<<dim3(3712), blk, 0, stream>>>(tab);

    dim3 gD(M_ROWS / 128, 512 / 64);     // 64 x 8
    dim3 gQ(M_ROWS / 128, 1536 / 64);    // 64 x 24  (fused QKV)
    dim3 gF(M_ROWS / 128, 1024 / 64);    // 64 x 16
    dim3 gA(S_LEN / 64, NHEAD, BATCH);   // 32 x 8 x 4
    dim3 gV(S_LEN / 64, BATCH * NHEAD);  // 32 x 32

    // h = x @ win_w + win_b + pos
    gemm_mfma<1><<<gD, blk, 0, stream>>>(x, nullptr, win_t, win_b, pos, H, M_ROWS, 512, 256);

    // local path: fused QKV (Q pre-scaled), V transpose, attention, Wo
    gemm_mfma<5><<<gQ, blk, 0, stream>>>(H, nullptr, lqkv_t, l_bqkv, nullptr, Qb, M_ROWS, 1536, 512);
    vtrans_kernel<<<gV, blk, 0, stream>>>(Vb, VT);
    attn_mfma<<<gA, blk, 0, stream>>>(Qb, Kb, VT, AO, 1);
    gemm_mfma<0><<<gD, blk, 0, stream>>>(AO, nullptr, lwo_t, l_bo, nullptr, LO, M_ROWS, 512, 512);

    // global path
    gemm_mfma<5><<<gQ, blk, 0, stream>>>(H, nullptr, gqkv_t, g_bqkv, nullptr, Qb, M_ROWS, 1536, 512);
    vtrans_kernel<<<gV, blk, 0, stream>>>(Vb, VT);
    attn_mfma<<<gA, blk, 0, stream>>>(Qb, Kb, VT, AO, 0);
    gemm_mfma<0><<<gD, blk, 0, stream>>>(AO, nullptr, gwo_t, g_bo, nullptr, GO, M_ROWS, 512, 512);

    // gate + fuse
    gemm_mfma<3><<<gD, blk, 0, stream>>>(LO, GO, gate_t, gate_b, nullptr, FUSED, M_ROWS, 512, 1024);

    // h1 = LN(h + fused)
    ln_res_kernel<<<M_ROWS / 4, blk, 0, stream>>>(H, FUSED, n1_g, n1_b, H1);

    // FFN
    gemm_mfma<2><<<gF, blk, 0, stream>>>(H1, nullptr, ffn1_t, ffn_b1, nullptr, FFNMID, M_ROWS, 1024, 512);
    gemm_mfma<0><<<gD, blk, 0, stream>>>(FFNMID, nullptr, ffn2_t, ffn_b2, nullptr, FFNOUT, M_ROWS, 512, 1024);

    // h2 = LN(LN(h1 + ffn, n2), n3)
    ln_double_kernel<<<M_ROWS / 4, blk, 0, stream>>>(H1, FFNOUT, n2_g, n2_b, n3_g, n3_b, H2);

    // pool + final projection
    hipMemsetAsync(POOLED, 0, BATCH * DMODEL * sizeof(float), stream);
    pool_kernel<<<dim3(BATCH * 16), blk, 0, stream>>>(H2, POOLED);
    out_kernel<<<dim3(BATCH), dim3(128), 0, stream>>>(POOLED, out_w, out_b, out);
}

// Round 5
// 374.002 us; speedup vs baseline: 1.7855x; 1.7855x over previous
//
#include <hip/hip_runtime.h>
#include <math.h>

#define S_LEN 2048
#define DMODEL 512
#define NHEAD 8
#define BATCH 4
#define M_ROWS (BATCH * S_LEN)   // 8192
#define UAC 4194304              // M_ROWS * DMODEL (elements per activation unit)

typedef __attribute__((ext_vector_type(8))) short frag8;   // 8 bf16 (4 VGPRs)
typedef __attribute__((ext_vector_type(4))) float f32x4;   // MFMA accumulator

__device__ inline unsigned short f2bf(float f) {
    unsigned int u = __float_as_uint(f);
    return (unsigned short)((u + 0x7FFFu + ((u >> 16) & 1u)) >> 16);  // RNE
}
__device__ inline float bf2f(unsigned short h) {
    return __uint_as_float(((unsigned int)h) << 16);
}

// ---------------------------------------------------------------------------
// Fused weight transpose+cast: 12 segments, one launch. W(K,N) f32 -> Wt(N,K) bf16.
// ---------------------------------------------------------------------------
struct WSeg { const float* src; unsigned short* dst; int K; int N; int start; };
struct WTab { WSeg s[12]; };

__global__ __launch_bounds__(256) void wcast_all(WTab tab)
{
    __shared__ float t[32][33];
    const int bid = blockIdx.x;
    int si = 0;
#pragma unroll
    for (int i = 1; i < 12; ++i) if (bid >= tab.s[i].start) si = i;
    const WSeg sg = tab.s[si];
    const int tile = bid - sg.start;
    const int nk = sg.K >> 5;
    const int k0 = (tile % nk) * 32, n0 = (tile / nk) * 32;
    {
        int kk = threadIdx.x >> 3, nq = (threadIdx.x & 7) * 4;
        float4 v = *(const float4*)&sg.src[(size_t)(k0 + kk) * sg.N + n0 + nq];
        t[kk][nq + 0] = v.x; t[kk][nq + 1] = v.y; t[kk][nq + 2] = v.z; t[kk][nq + 3] = v.w;
    }
    __syncthreads();
    {
        int n = threadIdx.x >> 3, kq = (threadIdx.x & 7) * 4;
        ushort4 o;
        o.x = f2bf(t[kq + 0][n]); o.y = f2bf(t[kq + 1][n]);
        o.z = f2bf(t[kq + 2][n]); o.w = f2bf(t[kq + 3][n]);
        *(ushort4*)&sg.dst[(size_t)(n0 + n) * sg.K + k0 + kq] = o;
    }
}

// ---------------------------------------------------------------------------
// V transpose: V(B,S,512) bf16 -> Vt(B*H, 64, S) bf16. grid (S/64, B*H).
// ---------------------------------------------------------------------------
__global__ __launch_bounds__(256) void vtrans_kernel(
    const unsigned short* __restrict__ V, unsigned short* __restrict__ Vt)
{
    __shared__ unsigned short T[64][72];
    const int st = blockIdx.x, bh = blockIdx.y;
    const int b = bh >> 3, h = bh & 7;
    const int tid = threadIdx.x;
    {
        const int s = tid >> 2, d0 = (tid & 3) * 16;
        const unsigned short* src = V + ((size_t)(b * S_LEN + st * 64 + s) * DMODEL + h * 64 + d0);
        *(uint4*)&T[s][d0] = *(const uint4*)src;
        *(uint4*)&T[s][d0 + 8] = *(const uint4*)(src + 8);
    }
    __syncthreads();
    {
        const int d = tid >> 2, s0 = (tid & 3) * 16;
        unsigned short buf[16];
#pragma unroll
        for (int j = 0; j < 16; ++j) buf[j] = T[s0 + j][d];
        unsigned short* dst = Vt + ((size_t)(bh * 64 + d) * S_LEN + st * 64 + s0);
        *(uint4*)&dst[0] = *(const uint4*)&buf[0];
        *(uint4*)&dst[8] = *(const uint4*)&buf[8];
    }
}

// ---------------------------------------------------------------------------
// MFMA GEMM with register-prefetch pipelining (named scalar regs — NO arrays,
// NO lambdas: R4's lambda-captured arrays were demoted to scratch, causing
// ~200 MB/dispatch of spill traffic. Macros keep everything in VGPRs).
// C = A(M,K) @ Wt(N,K)^T + bias.  Modes:
//   0: bias   1: bias+pos (A f32)   2: relu   3: gate blend (K=1024)
//   5: fused QKV (N=1536): out[mat*UAC + m*512 + (n&511)], mat0 (Q) scaled 1/8
// BM=128 BN=64 BK=64, 256 thr = 4 waves, wave tile 64x32.
// ---------------------------------------------------------------------------
#define GEMM_LOAD_A(K0)                                                          \
    do {                                                                         \
        if constexpr (MODE == 1) {                                               \
            const float* _s = (const float*)Av + (size_t)(bm + am) * K + (K0) + akh; \
            fa0 = *(const float4*)(_s + 0);  fa1 = *(const float4*)(_s + 4);     \
            fa2 = *(const float4*)(_s + 8);  fa3 = *(const float4*)(_s + 12);    \
            fa4 = *(const float4*)(_s + 16); fa5 = *(const float4*)(_s + 20);    \
            fa6 = *(const float4*)(_s + 24); fa7 = *(const float4*)(_s + 28);    \
        } else if constexpr (MODE == 3) {                                        \
            const int _kk = (K0) + akh;                                          \
            const unsigned short* _s = (_kk < Khalf)                             \
                ? (const unsigned short*)Av + (size_t)(bm + am) * Khalf + _kk    \
                : A2 + (size_t)(bm + am) * Khalf + (_kk - Khalf);                \
            ra0 = *(const uint4*)(_s + 0);  ra1 = *(const uint4*)(_s + 8);       \
            ra2 = *(const uint4*)(_s + 16); ra3 = *(const uint4*)(_s + 24);      \
        } else {                                                                 \
            const unsigned short* _s = (const unsigned short*)Av + (size_t)(bm + am) * K + (K0) + akh; \
            ra0 = *(const uint4*)(_s + 0);  ra1 = *(const uint4*)(_s + 8);       \
            ra2 = *(const uint4*)(_s + 16); ra3 = *(const uint4*)(_s + 24);      \
        }                                                                        \
    } while (0)

#define GEMM_LOAD_B(K0)                                                          \
    do {                                                                         \
        const unsigned short* _s = Wt + (size_t)(bn + bnr) * K + (K0) + bkq;     \
        rb0 = *(const uint4*)_s; rb1 = *(const uint4*)(_s + 8);                  \
    } while (0)

#define CVT8(dst_u4, v0, v1)                                                     \
    do {                                                                         \
        unsigned short _us[8];                                                   \
        _us[0] = f2bf(v0.x); _us[1] = f2bf(v0.y); _us[2] = f2bf(v0.z); _us[3] = f2bf(v0.w); \
        _us[4] = f2bf(v1.x); _us[5] = f2bf(v1.y); _us[6] = f2bf(v1.z); _us[7] = f2bf(v1.w); \
        dst_u4 = *(uint4*)_us;                                                   \
    } while (0)

template <int MODE>
__global__ __launch_bounds__(256) void gemm_mfma(
    const void* __restrict__ Av, const unsigned short* __restrict__ A2,
    const unsigned short* __restrict__ Wt, const float* __restrict__ bias,
    const float* __restrict__ pos, unsigned short* __restrict__ C,
    int M, int N, int K)
{
    __shared__ unsigned short As[128][72];
    __shared__ unsigned short Bs[64][72];
    const int tid = threadIdx.x;
    const int wave = tid >> 6, lane = tid & 63;
    const int lr = lane & 15, quad = lane >> 4, q8 = quad * 8;
    const int bm = blockIdx.x * 128, bn = blockIdx.y * 64;
    const int rm = (wave >> 1) * 64, rn = (wave & 1) * 32;
    const int Khalf = K >> 1;

    const int am = tid >> 1, akh = (tid & 1) * 32;     // A staging: row, k-offset
    const int bnr = tid >> 2, bkq = (tid & 3) * 16;    // B staging: row, k-offset

    uint4 ra0, ra1, ra2, ra3, rb0, rb1;
    float4 fa0, fa1, fa2, fa3, fa4, fa5, fa6, fa7;

    f32x4 acc[4][2];
#pragma unroll
    for (int t = 0; t < 4; ++t)
#pragma unroll
        for (int u = 0; u < 2; ++u) acc[t][u] = (f32x4){0.f, 0.f, 0.f, 0.f};

    GEMM_LOAD_A(0);
    GEMM_LOAD_B(0);
    for (int k0 = 0; k0 < K; k0 += 64) {
        if (k0) __syncthreads();       // previous iteration's frag reads complete
        if constexpr (MODE == 1) {
            uint4 w0, w1, w2, w3;
            CVT8(w0, fa0, fa1); CVT8(w1, fa2, fa3);
            CVT8(w2, fa4, fa5); CVT8(w3, fa6, fa7);
            *(uint4*)&As[am][akh + 0]  = w0; *(uint4*)&As[am][akh + 8]  = w1;
            *(uint4*)&As[am][akh + 16] = w2; *(uint4*)&As[am][akh + 24] = w3;
        } else {
            *(uint4*)&As[am][akh + 0]  = ra0; *(uint4*)&As[am][akh + 8]  = ra1;
            *(uint4*)&As[am][akh + 16] = ra2; *(uint4*)&As[am][akh + 24] = ra3;
        }
        *(uint4*)&Bs[bnr][bkq] = rb0;
        *(uint4*)&Bs[bnr][bkq + 8] = rb1;
        if (k0 + 64 < K) { GEMM_LOAD_A(k0 + 64); GEMM_LOAD_B(k0 + 64); }
        __syncthreads();
#pragma unroll
        for (int kc = 0; kc < 2; ++kc) {
            frag8 af[4], bfr[2];
#pragma unroll
            for (int t = 0; t < 4; ++t)
                af[t] = *(const frag8*)&As[rm + t * 16 + lr][kc * 32 + q8];
#pragma unroll
            for (int u = 0; u < 2; ++u)
                bfr[u] = *(const frag8*)&Bs[rn + u * 16 + lr][kc * 32 + q8];
#pragma unroll
            for (int t = 0; t < 4; ++t)
#pragma unroll
                for (int u = 0; u < 2; ++u)
                    acc[t][u] = __builtin_amdgcn_mfma_f32_16x16x32_bf16(
                        af[t], bfr[u], acc[t][u], 0, 0, 0);
        }
    }

    // ---- epilogue ----
#pragma unroll
    for (int t = 0; t < 4; ++t) {
#pragma unroll
        for (int i = 0; i < 4; ++i) {
            const int m = bm + rm + t * 16 + quad * 4 + i;
#pragma unroll
            for (int u = 0; u < 2; ++u) {
                const int n = bn + rn + u * 16 + lr;
                float v = acc[t][u][i] + bias[n];
                if constexpr (MODE == 1) v += pos[(size_t)(m & (S_LEN - 1)) * N + n];
                if constexpr (MODE == 2) v = fmaxf(v, 0.0f);
                if constexpr (MODE == 3) {
                    float g = tanhf(fmaxf(v, 0.0f));
                    float lo = bf2f(((const unsigned short*)Av)[(size_t)m * Khalf + n]);
                    float go = bf2f(A2[(size_t)m * Khalf + n]);
                    v = g * lo + (1.0f - g) * go;
                }
                if constexpr (MODE == 5) {
                    const int mat = n >> 9;
                    if (mat == 0) v *= 0.125f;          // fold attn scale into Q
                    C[(size_t)mat * UAC + (size_t)m * DMODEL + (n & 511)] = f2bf(v);
                } else {
                    C[(size_t)m * N + n] = f2bf(v);
                }
            }
        }
    }
}

// ---------------------------------------------------------------------------
// MFMA flash attention, transposed-S formulation, max-free softmax.
// Q,K: (B,S,512) bf16 (Q pre-scaled by 1/8); Vt: (B*H,64,S) bf16; O: (B,S,512).
// Block = 256 thr = 4 waves; wave handles 16 q-rows; 64x64 tiles.
// S^T = K·Q^T puts 4 consecutive c per lane -> P written with ds_write_b64.
// Ps is wave-private (doubles as Q staging). K/Vt staged with named-reg prefetch.
// ---------------------------------------------------------------------------
__global__ __launch_bounds__(256) void attn_mfma(
    const unsigned short* __restrict__ Q, const unsigned short* __restrict__ Kv,
    const unsigned short* __restrict__ Vt, unsigned short* __restrict__ O, int masked)
{
    __shared__ unsigned short Ks[64][72];   // [c][d]
    __shared__ unsigned short Vts[64][72];  // [d][c]
    __shared__ unsigned short Ps[64][72];   // [q][c]; also Q staging [q][d]
    const int qt = blockIdx.x, h = blockIdx.y, b = blockIdx.z;
    const int tid = threadIdx.x;
    const int wave = tid >> 6, lane = tid & 63;
    const int lr = lane & 15, quad = lane >> 4, q8 = quad * 8;

    // stage Q (wave-private rows) and hoist fragments
    {
        const int q = tid >> 2, d0 = (tid & 3) * 16;
        const unsigned short* src = Q + ((size_t)(b * S_LEN + qt * 64 + q) * DMODEL + h * 64 + d0);
        *(uint4*)&Ps[q][d0] = *(const uint4*)src;
        *(uint4*)&Ps[q][d0 + 8] = *(const uint4*)(src + 8);
    }
    frag8 qf[2];
    qf[0] = *(const frag8*)&Ps[wave * 16 + lr][q8];
    qf[1] = *(const frag8*)&Ps[wave * 16 + lr][32 + q8];

    f32x4 oacc[4];
#pragma unroll
    for (int t = 0; t < 4; ++t) oacc[t] = (f32x4){0.f, 0.f, 0.f, 0.f};
    float l_r = 0.f;                       // per-lane partial row sum (row = lr)

    int kt0 = 0, kt1 = S_LEN / 64 - 1;
    if (masked) { kt0 = qt > 0 ? qt - 1 : 0; kt1 = qt < 31 ? qt + 1 : 31; }

    // K/Vt staging coords + named prefetch registers
    const int sc = tid >> 2, sd0 = (tid & 3) * 16;
    const unsigned short* kbase = Kv + ((size_t)(b * S_LEN + sc) * DMODEL + h * 64 + sd0);
    const unsigned short* vbase = Vt + ((size_t)((b * 8 + h) * 64 + sc) * S_LEN + sd0);
    uint4 rk0, rk1, rv0, rv1;
    {
        const unsigned short* ksrc = kbase + (size_t)kt0 * 64 * DMODEL;
        rk0 = *(const uint4*)ksrc; rk1 = *(const uint4*)(ksrc + 8);
        const unsigned short* vsrc = vbase + kt0 * 64;
        rv0 = *(const uint4*)vsrc; rv1 = *(const uint4*)(vsrc + 8);
    }

    for (int kt = kt0; kt <= kt1; ++kt) {
        if (kt > kt0) __syncthreads();     // prev iteration's frag reads done
        *(uint4*)&Ks[sc][sd0] = rk0;  *(uint4*)&Ks[sc][sd0 + 8] = rk1;
        *(uint4*)&Vts[sc][sd0] = rv0; *(uint4*)&Vts[sc][sd0 + 8] = rv1;
        if (kt < kt1) {
            const unsigned short* ksrc = kbase + (size_t)(kt + 1) * 64 * DMODEL;
            rk0 = *(const uint4*)ksrc; rk1 = *(const uint4*)(ksrc + 8);
            const unsigned short* vsrc = vbase + (kt + 1) * 64;
            rv0 = *(const uint4*)vsrc; rv1 = *(const uint4*)(vsrc + 8);
        }
        __syncthreads();

        // ---- S^T = K Q^T : lane holds S[q=lr][c = t*16 + quad*4 + i] ----
        f32x4 sacc[4];
#pragma unroll
        for (int t = 0; t < 4; ++t) sacc[t] = (f32x4){0.f, 0.f, 0.f, 0.f};
#pragma unroll
        for (int kc = 0; kc < 2; ++kc) {
#pragma unroll
            for (int t = 0; t < 4; ++t) {
                frag8 kf = *(const frag8*)&Ks[t * 16 + lr][kc * 32 + q8];
                sacc[t] = __builtin_amdgcn_mfma_f32_16x16x32_bf16(kf, qf[kc], sacc[t], 0, 0, 0);
            }
        }

        // ---- max-free softmax; contiguous-c pack -> one b64 write per t ----
#pragma unroll
        for (int t = 0; t < 4; ++t) {
            float p[4];
#pragma unroll
            for (int i = 0; i < 4; ++i) p[i] = __expf(sacc[t][i]);
            if (masked) {
                const int qa = qt * 64 + wave * 16 + lr;
                const int ca = kt * 64 + t * 16 + quad * 4;
#pragma unroll
                for (int i = 0; i < 4; ++i) {
                    const int d = qa - (ca + i);
                    if (d > 32 || d < -32) p[i] = 0.f;
                }
            }
            l_r += (p[0] + p[1]) + (p[2] + p[3]);
            ushort4 pk;
            pk.x = f2bf(p[0]); pk.y = f2bf(p[1]); pk.z = f2bf(p[2]); pk.w = f2bf(p[3]);
            *(ushort4*)&Ps[wave * 16 + lr][t * 16 + quad * 4] = pk;
        }
        // no barrier: Ps rows [16w,16w+16) written and read only by wave w

        // ---- O += P V ----
#pragma unroll
        for (int cc = 0; cc < 2; ++cc) {
            frag8 pa = *(const frag8*)&Ps[wave * 16 + lr][cc * 32 + q8];
#pragma unroll
            for (int t = 0; t < 4; ++t) {
                frag8 vf = *(const frag8*)&Vts[t * 16 + lr][cc * 32 + q8];
                oacc[t] = __builtin_amdgcn_mfma_f32_16x16x32_bf16(pa, vf, oacc[t], 0, 0, 0);
            }
        }
    }

    // ---- one deferred row-sum reduction + epilogue ----
    l_r += __shfl_xor(l_r, 16);
    l_r += __shfl_xor(l_r, 32);            // lanes with same lr now hold row-lr sum
#pragma unroll
    for (int i = 0; i < 4; ++i) {
        const float inv = 1.0f / __shfl(l_r, quad * 4 + i);
        const int q = qt * 64 + wave * 16 + quad * 4 + i;
#pragma unroll
        for (int t = 0; t < 4; ++t)
            O[(size_t)(b * S_LEN + q) * DMODEL + h * 64 + t * 16 + lr] = f2bf(oacc[t][i] * inv);
    }
}

// ---------------------------------------------------------------------------
// LayerNorm (bf16 in/out, fp32 math): 256-thr blocks, one wave per row.
// ---------------------------------------------------------------------------
__device__ inline float wave_sum64(float v) {
#pragma unroll
    for (int off = 1; off < 64; off <<= 1) v += __shfl_xor(v, off);
    return v;
}

__global__ __launch_bounds__(256) void ln_res_kernel(
    const unsigned short* __restrict__ A, const unsigned short* __restrict__ Bb,
    const float* __restrict__ g, const float* __restrict__ be,
    unsigned short* __restrict__ out)
{
    const size_t row = blockIdx.x * 4 + (threadIdx.x >> 6);
    const int lane = threadIdx.x & 63;
    float x[8]; float s = 0.f;
#pragma unroll
    for (int k = 0; k < 8; ++k) {
        size_t idx = row * DMODEL + k * 64 + lane;
        x[k] = bf2f(A[idx]) + bf2f(Bb[idx]);
        s += x[k];
    }
    s = wave_sum64(s);
    float mean = s * (1.0f / DMODEL);
    float v = 0.f;
#pragma unroll
    for (int k = 0; k < 8; ++k) { float d = x[k] - mean; v += d * d; }
    v = wave_sum64(v) * (1.0f / DMODEL);
    float r = rsqrtf(v + 1e-5f);
#pragma unroll
    for (int k = 0; k < 8; ++k)
        out[row * DMODEL + k * 64 + lane] =
            f2bf((x[k] - mean) * r * g[k * 64 + lane] + be[k * 64 + lane]);
}

__global__ __launch_bounds__(256) void ln_double_kernel(
    const unsigned short* __restrict__ A, const unsigned short* __restrict__ Bb,
    const float* __restrict__ g2, const float* __restrict__ b2,
    const float* __restrict__ g3, const float* __restrict__ b3,
    unsigned short* __restrict__ out)
{
    const size_t row = blockIdx.x * 4 + (threadIdx.x >> 6);
    const int lane = threadIdx.x & 63;
    float x[8]; float s = 0.f;
#pragma unroll
    for (int k = 0; k < 8; ++k) {
        size_t idx = row * DMODEL + k * 64 + lane;
        x[k] = bf2f(A[idx]) + bf2f(Bb[idx]);
        s += x[k];
    }
    s = wave_sum64(s);
    float mean = s * (1.0f / DMODEL);
    float v = 0.f;
#pragma unroll
    for (int k = 0; k < 8; ++k) { float d = x[k] - mean; v += d * d; }
    v = wave_sum64(v) * (1.0f / DMODEL);
    float r = rsqrtf(v + 1e-5f);
    float t[8]; float s2 = 0.f;
#pragma unroll
    for (int k = 0; k < 8; ++k) {
        t[k] = (x[k] - mean) * r * g2[k * 64 + lane] + b2[k * 64 + lane];
        s2 += t[k];
    }
    s2 = wave_sum64(s2);
    float mean2 = s2 * (1.0f / DMODEL);
    float v2 = 0.f;
#pragma unroll
    for (int k = 0; k < 8; ++k) { float d = t[k] - mean2; v2 += d * d; }
    v2 = wave_sum64(v2) * (1.0f / DMODEL);
    float r2 = rsqrtf(v2 + 1e-5f);
#pragma unroll
    for (int k = 0; k < 8; ++k)
        out[row * DMODEL + k * 64 + lane] =
            f2bf((t[k] - mean2) * r2 * g3[k * 64 + lane] + b3[k * 64 + lane]);
}

// ---------------------------------------------------------------------------
// Mean-pool over S (bf16 in, fp32 atomics) + tiny final GEMM (fp32).
// ---------------------------------------------------------------------------
__global__ __launch_bounds__(256) void pool_kernel(
    const unsigned short* __restrict__ h2, float* __restrict__ pooled)
{
    const int b = blockIdx.x >> 4;
    const int chunk = blockIdx.x & 15;
    const int tid = threadIdx.x;
    float s0 = 0.f, s1 = 0.f;
    size_t base = (size_t)(b * S_LEN + chunk * 128) * DMODEL;
    for (int r = 0; r < 128; ++r) {
        s0 += bf2f(h2[base + (size_t)r * DMODEL + tid]);
        s1 += bf2f(h2[base + (size_t)r * DMODEL + 256 + tid]);
    }
    atomicAdd(&pooled[b * DMODEL + tid], s0);
    atomicAdd(&pooled[b * DMODEL + 256 + tid], s1);
}

__global__ __launch_bounds__(128) void out_kernel(
    const float* __restrict__ pooled, const float* __restrict__ w,
    const float* __restrict__ bias, float* __restrict__ out)
{
    const int b = blockIdx.x;
    const int o = threadIdx.x;
    float acc = 0.f;
    for (int d = 0; d < DMODEL; ++d)
        acc += pooled[b * DMODEL + d] * w[d * 128 + o];
    out[b * 128 + o] = acc * (1.0f / S_LEN) + bias[o];
}

// ---------------------------------------------------------------------------
extern "C" void kernel_launch(void* const* d_in, const int* in_sizes, int n_in,
                              void* d_out, int out_size, void* d_ws, size_t ws_size,
                              hipStream_t stream)
{
    const float* x      = (const float*)d_in[0];
    const float* pos    = (const float*)d_in[1];
    const float* win_w  = (const float*)d_in[2];
    const float* win_b  = (const float*)d_in[3];
    const float* l_wqkv = (const float*)d_in[4];
    const float* l_bqkv = (const float*)d_in[5];
    const float* l_wo   = (const float*)d_in[6];
    const float* l_bo   = (const float*)d_in[7];
    const float* g_wqkv = (const float*)d_in[8];
    const float* g_bqkv = (const float*)d_in[9];
    const float* g_wo   = (const float*)d_in[10];
    const float* g_bo   = (const float*)d_in[11];
    const float* gate_w = (const float*)d_in[12];
    const float* gate_b = (const float*)d_in[13];
    const float* ffn_w1 = (const float*)d_in[14];
    const float* ffn_b1 = (const float*)d_in[15];
    const float* ffn_w2 = (const float*)d_in[16];
    const float* ffn_b2 = (const float*)d_in[17];
    const float* n1_g   = (const float*)d_in[18];
    const float* n1_b   = (const float*)d_in[19];
    const float* n2_g   = (const float*)d_in[20];
    const float* n2_b   = (const float*)d_in[21];
    const float* n3_g   = (const float*)d_in[22];
    const float* n3_b   = (const float*)d_in[23];
    const float* out_w  = (const float*)d_in[24];
    const float* out_b  = (const float*)d_in[25];
    float* out = (float*)d_out;

    unsigned short* ws16 = (unsigned short*)d_ws;
    const size_t UA = (size_t)UAC;
    unsigned short* H  = ws16 + 0 * UA;
    unsigned short* Qb = ws16 + 1 * UA;
    unsigned short* Kb = ws16 + 2 * UA;
    unsigned short* Vb = ws16 + 3 * UA;
    unsigned short* AO = ws16 + 4 * UA;
    unsigned short* LO = ws16 + 5 * UA;
    unsigned short* VT = ws16 + 6 * UA;     // transposed V (B*H,64,S)
    unsigned short* GO     = Qb;            // Q dead after global attn
    unsigned short* FUSED  = Kb;            // K dead after global attn
    unsigned short* H1     = Vb;            // V dead after global attn
    unsigned short* FFNMID = AO;            // spans units 4..5
    unsigned short* FFNOUT = Qb;            // GO dead after gate
    unsigned short* H2     = Kb;            // FUSED dead after LN1
    float* POOLED = (float*)(void*)H;       // H dead after LN1

    // transposed bf16 weights
    unsigned short* wt = ws16 + 7 * UA;
    unsigned short* win_t  = wt;                      // 512 x 256
    unsigned short* lqkv_t = win_t  + 131072;         // 3 x (512 x 512)
    unsigned short* lwo_t  = lqkv_t + 786432;
    unsigned short* gqkv_t = lwo_t  + 262144;
    unsigned short* gwo_t  = gqkv_t + 786432;
    unsigned short* gate_t = gwo_t  + 262144;         // 512 x 1024
    unsigned short* ffn1_t = gate_t + 524288;         // 1024 x 512
    unsigned short* ffn2_t = ffn1_t + 524288;         // 512 x 1024

    WTab tab;
    tab.s[0]  = {win_w,             win_t,             256,  512,    0};
    tab.s[1]  = {l_wqkv + 0*262144, lqkv_t + 0*262144, 512,  512,  128};
    tab.s[2]  = {l_wqkv + 1*262144, lqkv_t + 1*262144, 512,  512,  384};
    tab.s[3]  = {l_wqkv + 2*262144, lqkv_t + 2*262144, 512,  512,  640};
    tab.s[4]  = {l_wo,              lwo_t,             512,  512,  896};
    tab.s[5]  = {g_wqkv + 0*262144, gqkv_t + 0*262144, 512,  512, 1152};
    tab.s[6]  = {g_wqkv + 1*262144, gqkv_t + 1*262144, 512,  512, 1408};
    tab.s[7]  = {g_wqkv + 2*262144, gqkv_t + 2*262144, 512,  512, 1664};
    tab.s[8]  = {g_wo,              gwo_t,             512,  512, 1920};
    tab.s[9]  = {gate_w,            gate_t,            1024, 512, 2176};
    tab.s[10] = {ffn_w1,            ffn1_t,            512, 1024, 2688};
    tab.s[11] = {ffn_w2,            ffn2_t,            1024, 512, 3200};

    dim3 blk(256);
    wcast_all<<<dim3(3712), blk, 0, stream>>>(tab);

    dim3 gD(M_ROWS / 128, 512 / 64);     // 64 x 8
    dim3 gQ(M_ROWS / 128, 1536 / 64);    // 64 x 24  (fused QKV)
    dim3 gF(M_ROWS / 128, 1024 / 64);    // 64 x 16
    dim3 gA(S_LEN / 64, NHEAD, BATCH);   // 32 x 8 x 4
    dim3 gV(S_LEN / 64, BATCH * NHEAD);  // 32 x 32

    // h = x @ win_w + win_b + pos
    gemm_mfma<1><<<gD, blk, 0, stream>>>(x, nullptr, win_t, win_b, pos, H, M_ROWS, 512, 256);

    // local path: fused QKV (Q pre-scaled), V transpose, attention, Wo
    gemm_mfma<5><<<gQ, blk, 0, stream>>>(H, nullptr, lqkv_t, l_bqkv, nullptr, Qb, M_ROWS, 1536, 512);
    vtrans_kernel<<<gV, blk, 0, stream>>>(Vb, VT);
    attn_mfma<<<gA, blk, 0, stream>>>(Qb, Kb, VT, AO, 1);
    gemm_mfma<0><<<gD, blk, 0, stream>>>(AO, nullptr, lwo_t, l_bo, nullptr, LO, M_ROWS, 512, 512);

    // global path
    gemm_mfma<5><<<gQ, blk, 0, stream>>>(H, nullptr, gqkv_t, g_bqkv, nullptr, Qb, M_ROWS, 1536, 512);
    vtrans_kernel<<<gV, blk, 0, stream>>>(Vb, VT);
    attn_mfma<<<gA, blk, 0, stream>>>(Qb, Kb, VT, AO, 0);
    gemm_mfma<0><<<gD, blk, 0, stream>>>(AO, nullptr, gwo_t, g_bo, nullptr, GO, M_ROWS, 512, 512);

    // gate + fuse
    gemm_mfma<3><<<gD, blk, 0, stream>>>(LO, GO, gate_t, gate_b, nullptr, FUSED, M_ROWS, 512, 1024);

    // h1 = LN(h + fused)
    ln_res_kernel<<<M_ROWS / 4, blk, 0, stream>>>(H, FUSED, n1_g, n1_b, H1);

    // FFN
    gemm_mfma<2><<<gF, blk, 0, stream>>>(H1, nullptr, ffn1_t, ffn_b1, nullptr, FFNMID, M_ROWS, 1024, 512);
    gemm_mfma<0><<<gD, blk, 0, stream>>>(FFNMID, nullptr, ffn2_t, ffn_b2, nullptr, FFNOUT, M_ROWS, 512, 1024);

    // h2 = LN(LN(h1 + ffn, n2), n3)
    ln_double_kernel<<<M_ROWS / 4, blk, 0, stream>>>(H1, FFNOUT, n2_g, n2_b, n3_g, n3_b, H2);

    // pool + final projection
    hipMemsetAsync(POOLED, 0, BATCH * DMODEL * sizeof(float), stream);
    pool_kernel<<<dim3(BATCH * 16), blk, 0, stream>>>(H2, POOLED);
    out_kernel<<<dim3(BATCH), dim3(128), 0, stream>>>(POOLED, out_w, out_b, out);
}